// Round 5
// baseline (954.344 us; speedup 1.0000x reference)
//
#include <hip/hip_runtime.h>
#include <stdint.h>
#include <stddef.h>

typedef _Float16 half_t;
typedef _Float16 half8 __attribute__((ext_vector_type(8)));
typedef float float4v __attribute__((ext_vector_type(4)));

#define D_DIM 1792
#define B_DIM 8192
#define LD D_DIM

// ---------------------------------------------------------------------------
// Async global->LDS staging of ROWS*32 fp16 tile (rows along K, NT layout).
// slot = chunk ^ ((row>>1)&3): every 8-lane b128 phase covers all 8 bank-quads
// (conflict-free — verified: SQ_LDS_BANK_CONFLICT 6.4e6 -> 0).
// Block-cooperative version (256 threads).
// ---------------------------------------------------------------------------
__device__ __forceinline__ void stage_rows(const half_t* __restrict__ src, int row0, int ld,
                                           int k0, half_t* dst, int nchunks, int tid) {
  for (int base = 0; base < nchunks; base += 256) {
    int ch  = base + tid;
    int row = ch >> 2, kc = ch & 3;
    int swz = kc ^ ((row >> 1) & 3);
    const half_t* g = src + (size_t)(row0 + row) * ld + k0 + swz * 8;
    half_t* l = dst + (size_t)(base + (tid & 192)) * 8;   // wave-uniform base; HW adds lane*16B
    __builtin_amdgcn_global_load_lds(
        (const __attribute__((address_space(1))) uint32_t*)(const void*)g,
        (__attribute__((address_space(3))) uint32_t*)(void*)l, 16, 0, 0);
  }
}

// Wave-private version: ONE wave stages its own tile (64-chunk stride).
// Self-synchronized by that wave's own vmcnt(0) — no barriers needed.
__device__ __forceinline__ void stage_wave(const half_t* __restrict__ src, int row0, int ld,
                                           int k0, half_t* dst, int nchunks, int lane) {
  for (int base = 0; base < nchunks; base += 64) {
    int ch  = base + lane;
    int row = ch >> 2, kc = ch & 3;
    int swz = kc ^ ((row >> 1) & 3);
    const half_t* g = src + (size_t)(row0 + row) * ld + k0 + swz * 8;
    half_t* l = dst + (size_t)base * 8;                   // wave-uniform; HW adds lane*16B
    __builtin_amdgcn_global_load_lds(
        (const __attribute__((address_space(1))) uint32_t*)(const void*)g,
        (__attribute__((address_space(3))) uint32_t*)(void*)l, 16, 0, 0);
  }
}

__device__ __forceinline__ half8 frag32(const half_t* lds, int row, int chunk) {
  int slot = chunk ^ ((row >> 1) & 3);
  return *(const half8*)(lds + row * 32 + slot * 8);
}
// 128-wide LDS rows (Us / Dinv in the solve): 2-way aliasing only (free).
__device__ __forceinline__ half8 frag128(const half_t* lds, int row, int chunk) {
  int slot = chunk ^ (row & 15);
  return *(const half8*)(lds + row * 128 + slot * 8);
}

// ---------------------------------------------------------------------------
// 1. Row-normalize U -> Vh (fp16). One block per row.
// ---------------------------------------------------------------------------
__global__ __launch_bounds__(256) void normalize_rows(const float* __restrict__ U,
                                                      half_t* __restrict__ Vh) {
  int r = blockIdx.x, t = threadIdx.x;
  float v[7];
  float s = 0.f;
#pragma unroll
  for (int i = 0; i < 7; ++i) {
    v[i] = U[(size_t)r * D_DIM + t + i * 256];
    s += v[i] * v[i];
  }
#pragma unroll
  for (int m = 32; m; m >>= 1) s += __shfl_xor(s, m);
  __shared__ float red[4];
  __shared__ float tot;
  if ((t & 63) == 0) red[t >> 6] = s;
  __syncthreads();
  if (t == 0) tot = 1.0f / sqrtf(red[0] + red[1] + red[2] + red[3]);
  __syncthreads();
  float rn = tot;
#pragma unroll
  for (int i = 0; i < 7; ++i)
    Vh[(size_t)r * D_DIM + t + i * 256] = (half_t)(v[i] * rn);
}

// ---------------------------------------------------------------------------
// 2. Transpose X (fp32, D x B) -> XT (fp16, B x D). 64x64 LDS tiles.
// ---------------------------------------------------------------------------
__global__ __launch_bounds__(256) void transpose_x(const float* __restrict__ X,
                                                   half_t* __restrict__ XT) {
  __shared__ half_t t[64][68];
  int r0 = blockIdx.x * 64, c0 = blockIdx.y * 64;
  int tid = threadIdx.x;
#pragma unroll
  for (int i = 0; i < 16; ++i) {
    int f = tid + i * 256;
    int rr = f >> 6, cc = f & 63;
    t[rr][cc] = (half_t)X[(size_t)(r0 + rr) * B_DIM + c0 + cc];
  }
  __syncthreads();
#pragma unroll
  for (int i = 0; i < 16; ++i) {
    int f = tid + i * 256;
    int cc = f >> 6, rr = f & 63;
    XT[(size_t)(c0 + cc) * D_DIM + r0 + rr] = t[rr][cc];
  }
}

// ---------------------------------------------------------------------------
// 2b. Transpose Vh (fp16, D x D) -> VhT.
// ---------------------------------------------------------------------------
__global__ __launch_bounds__(256) void transpose_h(const half_t* __restrict__ Vh,
                                                   half_t* __restrict__ VhT) {
  __shared__ half_t t[64][68];
  int r0 = blockIdx.x * 64, c0 = blockIdx.y * 64;
  int tid = threadIdx.x;
#pragma unroll
  for (int i = 0; i < 16; ++i) {
    int f = tid + i * 256;
    int rr = f >> 6, cc = f & 63;
    t[rr][cc] = Vh[(size_t)(r0 + rr) * D_DIM + c0 + cc];
  }
  __syncthreads();
#pragma unroll
  for (int i = 0; i < 16; ++i) {
    int f = tid + i * 256;
    int cc = f >> 6, rr = f & 63;
    VhT[(size_t)(c0 + cc) * D_DIM + r0 + rr] = t[rr][cc];
  }
}

// ---------------------------------------------------------------------------
// 3. Big NT MFMA GEMM: acc[m][n] = sum_k A[m][k]*B[n][k], 128x128 tile, BK=32.
//    MODE 0 (gram->T16): triangular block skip; Ch = (c<r) ? 2*acc : 0  (fp16)
//    MODE 1 (Pf build):  Ch = (r==c ? 1 : 0) - acc                      (fp16)
//    MODE 2 (final):     Cf = acc                                       (fp32)
// ---------------------------------------------------------------------------
template <int MODE>
__global__ __launch_bounds__(256) void gemm_nt(const half_t* __restrict__ A,
                                               const half_t* __restrict__ B,
                                               float* __restrict__ Cf, half_t* __restrict__ Ch,
                                               int K, int lda, int ldb, int ldc) {
  int m0 = blockIdx.y * 128, n0 = blockIdx.x * 128;
  if constexpr (MODE == 0) { if (n0 > m0) return; }   // gram: lower+diag blocks only
  __shared__ half_t sA[128 * 32];
  __shared__ half_t sB[128 * 32];
  int tid = threadIdx.x, lane = tid & 63, wave = tid >> 6;
  int ln15 = lane & 15, quad = lane >> 4;
  int wr = (wave & 1) * 64, wc = (wave >> 1) * 64;
  float4v acc[4][4] = {};
  for (int kb = 0; kb < K / 32; ++kb) {
    stage_rows(A, m0, lda, kb * 32, sA, 512, tid);
    stage_rows(B, n0, ldb, kb * 32, sB, 512, tid);
    __syncthreads();
    half8 af[4], bf[4];
#pragma unroll
    for (int i = 0; i < 4; ++i) af[i] = frag32(sA, wr + i * 16 + ln15, quad);
#pragma unroll
    for (int j = 0; j < 4; ++j) bf[j] = frag32(sB, wc + j * 16 + ln15, quad);
#pragma unroll
    for (int i = 0; i < 4; ++i)
#pragma unroll
      for (int j = 0; j < 4; ++j)
        acc[i][j] = __builtin_amdgcn_mfma_f32_16x16x32_f16(af[i], bf[j], acc[i][j], 0, 0, 0);
    __syncthreads();
  }
#pragma unroll
  for (int i = 0; i < 4; ++i)
#pragma unroll
    for (int j = 0; j < 4; ++j)
#pragma unroll
      for (int rg = 0; rg < 4; ++rg) {
        int row = m0 + wr + i * 16 + quad * 4 + rg;
        int col = n0 + wc + j * 16 + ln15;
        size_t idx = (size_t)row * ldc + col;
        float v = acc[i][j][rg];
        if constexpr (MODE == 0) Ch[idx] = (col < row) ? (half_t)(2.0f * v) : (half_t)0.0f;
        else if constexpr (MODE == 1) Ch[idx] = (half_t)(((row == col) ? 1.0f : 0.0f) - v);
        else Cf[idx] = v;
      }
}

// ---------------------------------------------------------------------------
// 4. Invert 14 diagonal 128x128 unit-lower-triangular blocks of T (from T16).
//    One wave per column; forward substitution. -> Dinv (fp16, 14x128x128)
// ---------------------------------------------------------------------------
__global__ __launch_bounds__(256) void diag_inv(const half_t* __restrict__ T16,
                                                half_t* __restrict__ Dinv) {
  int b = blockIdx.x >> 5;        // block 0..13
  int cg = blockIdx.x & 31;       // column group
  int wave = threadIdx.x >> 6, ln = threadIdx.x & 63;
  int c = cg * 4 + wave;          // this wave's column (0..127)
  __shared__ float Ls[128][128];
  __shared__ float xw[4][128];
  for (int i = 0; i < 64; ++i) {
    int f = threadIdx.x + i * 256;
    int r = f >> 7, cc = f & 127;
    Ls[r][cc] = (cc < r) ? (float)T16[(size_t)(b * 128 + r) * D_DIM + b * 128 + cc] : 0.0f;
  }
  __syncthreads();
  float xlo = (ln == 0) ? 1.f : 0.f, xhi = 0.f;
  for (int r = c + 1; r < 128; ++r) {
    float ta = 0.f;
    int j0 = c + ln, j1 = c + 64 + ln;
    if (j0 < r) ta += Ls[r][j0] * xlo;
    if (j1 < r) ta += Ls[r][j1] * xhi;
#pragma unroll
    for (int m = 32; m; m >>= 1) ta += __shfl_xor(ta, m);
    float xr = -ta;
    if (j0 == r) xlo = xr;
    if (j1 == r) xhi = xr;
    if (ln == 0) xw[wave][r] = xr;
  }
  __syncthreads();
  for (int rr = ln; rr < 128; rr += 64) {
    float val = (rr < c) ? 0.f : ((rr == c) ? 1.f : xw[wave][rr]);
    Dinv[(size_t)b * 16384 + (size_t)rr * 128 + c] = (half_t)val;
  }
}

// ---------------------------------------------------------------------------
// 5. FUSED blocked forward substitution — ONE launch.
//    R5: BARRIER-FREE, WAVE-PRIVATE K-loop. Evidence R1/R3/R4: every variant
//    where K-step consumers wait on memory inside a block-wide barrier
//    generation lands at ~2000+cy/iter (barrier couples 4 waves to the
//    slowest chain; compiler drains LDS-DMA conservatively for runtime-
//    indexed rings; direct per-lane loads scatter 16 rows/instr = worse).
//    Now: 8 waves/block, each wave owns K-chunks c == w (mod 8) and a
//    PRIVATE 10KB LDS buffer. A wave's own vmcnt(0) after its own DMA is
//    exactly the required wait (conservative == intended) and NO barrier
//    sits in the K-loop — latency hidden by 8 independent wave chains.
//    Panel end: 8 partial accs summed via LDS atomicAdd(f32), then
//    phase2 (Ut=2VnT-acc -> Us) and phase4 (x Dinv^T) as before.
//    Block = 32 m-rows (56 blocks, 512 thr). LDS 136KB static.
//    Per panel ib:
//      Ut[m][s] = 2*Vn[ib*128+s][m] - sum_{k<ib*128} WtT[m][k]*T16[ib*128+s][k]
//      WtT[m][ib*128+r] = sum_s Ut[m][s]*Dinv[ib][r][s]
// ---------------------------------------------------------------------------
__global__ __launch_bounds__(512, 1) void fused_solve(const half_t* __restrict__ T16,
                                                      const half_t* __restrict__ VhT,
                                                      const half_t* __restrict__ Dinv,
                                                      half_t* __restrict__ WtT) {
  __shared__ float  accbuf[32 * 128];          // 16KB fp32 cross-wave accumulator
  __shared__ half_t Us[32 * 128];              // 8KB  (phase 2 -> 4)
  __shared__ half_t sD[128 * 128];             // 32KB (staged at panel top)
  __shared__ half_t pbuf[8 * 5120];            // 80KB: per-wave A(1024h)+B(4096h)
  int tid = threadIdx.x, lane = tid & 63, w = tid >> 6;
  int ln15 = lane & 15, quad = lane >> 4;
  int m0 = blockIdx.x * 32;
  half_t* myA = pbuf + w * 5120;
  half_t* myB = myA + 1024;

  for (int ib = 0; ib < 14; ++ib) {
    // prev panel's WtT stores drained (vmcnt0) + phase-4 LDS reads done
    __syncthreads();
    // zero the cross-wave accumulator
#pragma unroll
    for (int i = 0; i < 8; ++i) accbuf[tid * 8 + i] = 0.f;
    // issue Dinv block ib DMA -> sD (drained by the pre-phase-4 syncthreads)
    for (int it = 0; it < 4; ++it) {
      int ch = it * 512 + tid;
      int row = ch >> 4, sc = ch & 15;
      const half_t* g = Dinv + (size_t)ib * 16384 + (size_t)row * 128 + ((sc ^ (row & 15)) << 3);
      half_t* l = sD + (size_t)(it * 512 + (tid & 448)) * 8;
      __builtin_amdgcn_global_load_lds(
          (const __attribute__((address_space(1))) uint32_t*)(const void*)g,
          (__attribute__((address_space(3))) uint32_t*)(void*)l, 16, 0, 0);
    }
    __syncthreads();   // accbuf zeros visible before any wave's atomicAdds

    int Kc = ib * 4;   // number of BK=32 chunks this panel
    if (Kc > 0) {
      float4v acc[2][8] = {};
      // wave-private K-loop: chunks c == w (mod 8); NO barriers inside.
      for (int c = w; c < Kc; c += 8) {
        stage_wave(WtT, m0, D_DIM, c * 32, myA, 128, lane);          // 2 loads/lane
        stage_wave(T16, ib * 128, D_DIM, c * 32, myB, 512, lane);    // 8 loads/lane
        asm volatile("s_waitcnt vmcnt(0)" ::: "memory");             // own loads only
        __builtin_amdgcn_sched_barrier(0);
        half8 af[2], bf[8];
#pragma unroll
        for (int i = 0; i < 2; ++i) af[i] = frag32(myA, i * 16 + ln15, quad);
#pragma unroll
        for (int j = 0; j < 8; ++j) bf[j] = frag32(myB, j * 16 + ln15, quad);
#pragma unroll
        for (int i = 0; i < 2; ++i)
#pragma unroll
          for (int j = 0; j < 8; ++j)
            acc[i][j] = __builtin_amdgcn_mfma_f32_16x16x32_f16(af[i], bf[j], acc[i][j], 0, 0, 0);
        // compiler's lgkmcnt before the last MFMA retires all ds_reads, so the
        // next iteration's DMA cannot overwrite data still being read.
      }
      // reduce this wave's partial into the shared fp32 accumulator
#pragma unroll
      for (int i = 0; i < 2; ++i)
#pragma unroll
        for (int j = 0; j < 8; ++j)
#pragma unroll
          for (int rg = 0; rg < 4; ++rg)
            atomicAdd(&accbuf[(i * 16 + quad * 4 + rg) * 128 + j * 16 + ln15],
                      acc[i][j][rg]);
    }
    __syncthreads();   // all partials visible (lgkmcnt drain + barrier)
    // phase 2: Ut = 2*VnT - acc -> Us (A-operand layout, swizzled). 512thr: 8 elems each.
    {
      int rl = tid >> 4, c8 = tid & 15;
      half8 vh = *(const half8*)(VhT + (size_t)(m0 + rl) * D_DIM + ib * 128 + c8 * 8);
      half8 us;
#pragma unroll
      for (int i = 0; i < 8; ++i)
        us[i] = (half_t)(2.f * (float)vh[i] - accbuf[rl * 128 + c8 * 8 + i]);
      *(half8*)(Us + rl * 128 + ((c8 ^ (rl & 15)) << 3)) = us;
    }
    __syncthreads();   // Us ds_writes + sD DMA (vmcnt0) drained
    // phase 4: WtT-panel(32x128) = Ut(32x128) * Dinv^T(128x128). wave w ->
    // m-half (w&1), s-quarter (w>>1): 2 output tiles, K=128.
    {
      int mh = (w & 1) * 16, sq = (w >> 1) * 32;
      float4v a2[2] = {};
#pragma unroll
      for (int kk = 0; kk < 4; ++kk) {
        half8 af = frag128(Us, mh + ln15, kk * 4 + quad);
#pragma unroll
        for (int j = 0; j < 2; ++j) {
          half8 bf = frag128(sD, sq + j * 16 + ln15, kk * 4 + quad);
          a2[j] = __builtin_amdgcn_mfma_f32_16x16x32_f16(af, bf, a2[j], 0, 0, 0);
        }
      }
#pragma unroll
      for (int j = 0; j < 2; ++j)
#pragma unroll
        for (int rg = 0; rg < 4; ++rg)
          WtT[(size_t)(m0 + mh + quad * 4 + rg) * D_DIM + ib * 128 + sq + j * 16 + ln15] =
              (half_t)a2[j][rg];
    }
  }
}

// ---------------------------------------------------------------------------
extern "C" void kernel_launch(void* const* d_in, const int* in_sizes, int n_in,
                              void* d_out, int out_size, void* d_ws, size_t ws_size,
                              hipStream_t stream) {
  (void)in_sizes; (void)n_in; (void)out_size; (void)ws_size;
  const float* X = (const float*)d_in[0];   // (1792, 8192) fp32
  const float* U = (const float*)d_in[1];   // (1792, 1792) fp32
  float* out = (float*)d_out;               // (1792, 8192) fp32

  char* ws = (char*)d_ws;
  half_t* XT   = (half_t*)(ws);                    // 29,360,128 B
  half_t* Vh   = (half_t*)(ws + 29360128);         //  6,422,528 B
  half_t* VhT  = (half_t*)(ws + 35782656);         //  6,422,528 B
  half_t* T16  = (half_t*)(ws + 42205184);         //  6,422,528 B
  half_t* WtT  = (half_t*)(ws + 48627712);         //  6,422,528 B
  half_t* Dinv = (half_t*)(ws + 55050240);         //    458,752 B
  half_t* Pf   = (half_t*)(ws + 55508992);         //  6,422,528 B  (total ~62 MB)

  normalize_rows<<<dim3(D_DIM), dim3(256), 0, stream>>>(U, Vh);
  transpose_x<<<dim3(D_DIM / 64, B_DIM / 64), dim3(256), 0, stream>>>(X, XT);
  // T16 = 2*strict_tril(Vn Vn^T) directly (gram fused with build_T16; fp32 G gone)
  gemm_nt<0><<<dim3(14, 14), dim3(256), 0, stream>>>(Vh, Vh, nullptr, T16,
                                                     D_DIM, D_DIM, D_DIM, D_DIM);
  transpose_h<<<dim3(28, 28), dim3(256), 0, stream>>>(Vh, VhT);
  diag_inv<<<dim3(448), dim3(256), 0, stream>>>(T16, Dinv);
  // one-launch blocked forward substitution: WtT = (T^{-1} 2Vn)^T
  fused_solve<<<dim3(56), dim3(512), 0, stream>>>(T16, VhT, Dinv, WtT);
  // Pf = I - Wt^T Vn :  Pf[m][n] = delta(m,n) - sum_k WtT[m][k]*VhT[n][k]
  gemm_nt<1><<<dim3(14, 14), dim3(256), 0, stream>>>(WtT, VhT, nullptr, Pf,
                                                     D_DIM, D_DIM, D_DIM, D_DIM);
  // out = Pf X :  out[i][j] = sum_k Pf[i][k]*XT[j][k]
  gemm_nt<2><<<dim3(64, 14), dim3(256), 0, stream>>>(Pf, XT, out, nullptr,
                                                     D_DIM, D_DIM, D_DIM, B_DIM);
}

// Round 6
// 555.865 us; speedup vs baseline: 1.7169x; 1.7169x over previous
//
#include <hip/hip_runtime.h>
#include <stdint.h>
#include <stddef.h>

typedef _Float16 half_t;
typedef _Float16 half8 __attribute__((ext_vector_type(8)));
typedef float float4v __attribute__((ext_vector_type(4)));

#define D_DIM 1792
#define B_DIM 8192
#define LD D_DIM

// ---------------------------------------------------------------------------
// Async global->LDS staging of ROWS*32 fp16 tile (rows along K, NT layout).
// slot = chunk ^ ((row>>1)&3): conflict-free (verified SQ_LDS_BANK_CONFLICT=0).
// Used by gemm_nt only (fused_solve no longer uses LDS-DMA in its K-loop:
// R1/R3/R5 measured ~2000+cy/K-step regardless of prefetch depth => per-CU
// LDS-DMA request-queue is the serializer, not the software pipeline).
// ---------------------------------------------------------------------------
__device__ __forceinline__ void stage_rows(const half_t* __restrict__ src, int row0, int ld,
                                           int k0, half_t* dst, int nchunks, int tid) {
  for (int base = 0; base < nchunks; base += 256) {
    int ch  = base + tid;
    int row = ch >> 2, kc = ch & 3;
    int swz = kc ^ ((row >> 1) & 3);
    const half_t* g = src + (size_t)(row0 + row) * ld + k0 + swz * 8;
    half_t* l = dst + (size_t)(base + (tid & 192)) * 8;   // wave-uniform base; HW adds lane*16B
    __builtin_amdgcn_global_load_lds(
        (const __attribute__((address_space(1))) uint32_t*)(const void*)g,
        (__attribute__((address_space(3))) uint32_t*)(void*)l, 16, 0, 0);
  }
}

__device__ __forceinline__ half8 frag32(const half_t* lds, int row, int chunk) {
  int slot = chunk ^ ((row >> 1) & 3);
  return *(const half8*)(lds + row * 32 + slot * 8);
}
// 64-wide LDS rows (fused_solve K-loop tiles): slot = chunk ^ (row&7).
// 16 lanes/quad read consecutive rows -> 8 distinct slots -> 2-way (free).
__device__ __forceinline__ half8 frag64(const half_t* lds, int row, int chunk) {
  int slot = chunk ^ (row & 7);
  return *(const half8*)(lds + row * 64 + slot * 8);
}
// 128-wide LDS rows (Us / Dinv in the solve): 2-way aliasing only (free).
__device__ __forceinline__ half8 frag128(const half_t* lds, int row, int chunk) {
  int slot = chunk ^ (row & 15);
  return *(const half8*)(lds + row * 128 + slot * 8);
}

// ---------------------------------------------------------------------------
// 1. Row-normalize U -> Vh (fp16). One block per row.
// ---------------------------------------------------------------------------
__global__ __launch_bounds__(256) void normalize_rows(const float* __restrict__ U,
                                                      half_t* __restrict__ Vh) {
  int r = blockIdx.x, t = threadIdx.x;
  float v[7];
  float s = 0.f;
#pragma unroll
  for (int i = 0; i < 7; ++i) {
    v[i] = U[(size_t)r * D_DIM + t + i * 256];
    s += v[i] * v[i];
  }
#pragma unroll
  for (int m = 32; m; m >>= 1) s += __shfl_xor(s, m);
  __shared__ float red[4];
  __shared__ float tot;
  if ((t & 63) == 0) red[t >> 6] = s;
  __syncthreads();
  if (t == 0) tot = 1.0f / sqrtf(red[0] + red[1] + red[2] + red[3]);
  __syncthreads();
  float rn = tot;
#pragma unroll
  for (int i = 0; i < 7; ++i)
    Vh[(size_t)r * D_DIM + t + i * 256] = (half_t)(v[i] * rn);
}

// ---------------------------------------------------------------------------
// 2. Transpose X (fp32, D x B) -> XT (fp16, B x D). 64x64 LDS tiles.
// ---------------------------------------------------------------------------
__global__ __launch_bounds__(256) void transpose_x(const float* __restrict__ X,
                                                   half_t* __restrict__ XT) {
  __shared__ half_t t[64][68];
  int r0 = blockIdx.x * 64, c0 = blockIdx.y * 64;
  int tid = threadIdx.x;
#pragma unroll
  for (int i = 0; i < 16; ++i) {
    int f = tid + i * 256;
    int rr = f >> 6, cc = f & 63;
    t[rr][cc] = (half_t)X[(size_t)(r0 + rr) * B_DIM + c0 + cc];
  }
  __syncthreads();
#pragma unroll
  for (int i = 0; i < 16; ++i) {
    int f = tid + i * 256;
    int cc = f >> 6, rr = f & 63;
    XT[(size_t)(c0 + cc) * D_DIM + r0 + rr] = t[rr][cc];
  }
}

// ---------------------------------------------------------------------------
// 2b. Transpose Vh (fp16, D x D) -> VhT.
// ---------------------------------------------------------------------------
__global__ __launch_bounds__(256) void transpose_h(const half_t* __restrict__ Vh,
                                                   half_t* __restrict__ VhT) {
  __shared__ half_t t[64][68];
  int r0 = blockIdx.x * 64, c0 = blockIdx.y * 64;
  int tid = threadIdx.x;
#pragma unroll
  for (int i = 0; i < 16; ++i) {
    int f = tid + i * 256;
    int rr = f >> 6, cc = f & 63;
    t[rr][cc] = Vh[(size_t)(r0 + rr) * D_DIM + c0 + cc];
  }
  __syncthreads();
#pragma unroll
  for (int i = 0; i < 16; ++i) {
    int f = tid + i * 256;
    int cc = f >> 6, rr = f & 63;
    VhT[(size_t)(c0 + cc) * D_DIM + r0 + rr] = t[rr][cc];
  }
}

// ---------------------------------------------------------------------------
// 3. Big NT MFMA GEMM: acc[m][n] = sum_k A[m][k]*B[n][k], 128x128 tile, BK=32.
//    MODE 0 (gram->T16): triangular block skip; Ch = (c<r) ? 2*acc : 0  (fp16)
//    MODE 1 (Pf build):  Ch = (r==c ? 1 : 0) - acc                      (fp16)
//    MODE 2 (final):     Cf = acc (fp32), XCD-swizzled blockIdx (896=8*112)
// ---------------------------------------------------------------------------
template <int MODE>
__global__ __launch_bounds__(256) void gemm_nt(const half_t* __restrict__ A,
                                               const half_t* __restrict__ B,
                                               float* __restrict__ Cf, half_t* __restrict__ Ch,
                                               int K, int lda, int ldb, int ldc) {
  int bx = blockIdx.x, by = blockIdx.y;
  if constexpr (MODE == 2) {
    // T1 XCD swizzle: 896 workgroups, 8 XCDs, 112/XCD (bijective).
    int id = bx + gridDim.x * by;
    int t = (id & 7) * 112 + (id >> 3);
    bx = t % gridDim.x;
    by = t / gridDim.x;
  }
  int m0 = by * 128, n0 = bx * 128;
  if constexpr (MODE == 0) { if (n0 > m0) return; }   // gram: lower+diag blocks only
  __shared__ half_t sA[128 * 32];
  __shared__ half_t sB[128 * 32];
  int tid = threadIdx.x, lane = tid & 63, wave = tid >> 6;
  int ln15 = lane & 15, quad = lane >> 4;
  int wr = (wave & 1) * 64, wc = (wave >> 1) * 64;
  float4v acc[4][4] = {};
  for (int kb = 0; kb < K / 32; ++kb) {
    stage_rows(A, m0, lda, kb * 32, sA, 512, tid);
    stage_rows(B, n0, ldb, kb * 32, sB, 512, tid);
    __syncthreads();
    half8 af[4], bf[4];
#pragma unroll
    for (int i = 0; i < 4; ++i) af[i] = frag32(sA, wr + i * 16 + ln15, quad);
#pragma unroll
    for (int j = 0; j < 4; ++j) bf[j] = frag32(sB, wc + j * 16 + ln15, quad);
#pragma unroll
    for (int i = 0; i < 4; ++i)
#pragma unroll
      for (int j = 0; j < 4; ++j)
        acc[i][j] = __builtin_amdgcn_mfma_f32_16x16x32_f16(af[i], bf[j], acc[i][j], 0, 0, 0);
    __syncthreads();
  }
#pragma unroll
  for (int i = 0; i < 4; ++i)
#pragma unroll
    for (int j = 0; j < 4; ++j)
#pragma unroll
      for (int rg = 0; rg < 4; ++rg) {
        int row = m0 + wr + i * 16 + quad * 4 + rg;
        int col = n0 + wc + j * 16 + ln15;
        size_t idx = (size_t)row * ldc + col;
        float v = acc[i][j][rg];
        if constexpr (MODE == 0) Ch[idx] = (col < row) ? (half_t)(2.0f * v) : (half_t)0.0f;
        else if constexpr (MODE == 1) Ch[idx] = (half_t)(((row == col) ? 1.0f : 0.0f) - v);
        else Cf[idx] = v;
      }
}

// ---------------------------------------------------------------------------
// 4. Invert 14 diagonal 128x128 unit-lower-triangular blocks of T (from T16).
//    One wave per column; forward substitution. -> Dinv (fp16, 14x128x128)
// ---------------------------------------------------------------------------
__global__ __launch_bounds__(256) void diag_inv(const half_t* __restrict__ T16,
                                                half_t* __restrict__ Dinv) {
  int b = blockIdx.x >> 5;        // block 0..13
  int cg = blockIdx.x & 31;       // column group
  int wave = threadIdx.x >> 6, ln = threadIdx.x & 63;
  int c = cg * 4 + wave;          // this wave's column (0..127)
  __shared__ float Ls[128][128];
  __shared__ float xw[4][128];
  for (int i = 0; i < 64; ++i) {
    int f = threadIdx.x + i * 256;
    int r = f >> 7, cc = f & 127;
    Ls[r][cc] = (cc < r) ? (float)T16[(size_t)(b * 128 + r) * D_DIM + b * 128 + cc] : 0.0f;
  }
  __syncthreads();
  float xlo = (ln == 0) ? 1.f : 0.f, xhi = 0.f;
  for (int r = c + 1; r < 128; ++r) {
    float ta = 0.f;
    int j0 = c + ln, j1 = c + 64 + ln;
    if (j0 < r) ta += Ls[r][j0] * xlo;
    if (j1 < r) ta += Ls[r][j1] * xhi;
#pragma unroll
    for (int m = 32; m; m >>= 1) ta += __shfl_xor(ta, m);
    float xr = -ta;
    if (j0 == r) xlo = xr;
    if (j1 == r) xhi = xr;
    if (ln == 0) xw[wave][r] = xr;
  }
  __syncthreads();
  for (int rr = ln; rr < 128; rr += 64) {
    float val = (rr < c) ? 0.f : ((rr == c) ? 1.f : xw[wave][rr]);
    Dinv[(size_t)b * 16384 + (size_t)rr * 128 + c] = (half_t)val;
  }
}

// ---------------------------------------------------------------------------
// 5. FUSED blocked forward substitution — ONE launch.
//    R6: REG-STAGED K-loop (global->VGPR->ds_write), 4-deep pipeline.
//    Evidence R1/R3/R5: any K-loop built on global_load_lds saturates at
//    ~2000cy/step independent of prefetch depth (per-CU LDS-DMA request
//    queue serializes; depth lives in the queue, not the program). R4:
//    per-lane direct-to-reg fragments scatter 16 rows/instr — worse.
//    Here: 6 contiguous 16B loads/thread/step into 4 statically-named
//    register groups (rule #20), counted vmcnt(18/12/6/0), ds_write to a
//    2-deep LDS buffer, 2 cheap barriers/step. Normal VMEM queueing is
//    per-wave and deep — no DMA engine in the path. sD keeps one-shot DMA
//    (outside the loop, drained by the pre-phase-4 syncthreads).
//    Per panel ib:
//      Ut[m][s] = 2*Vn[ib*128+s][m] - sum_{k<ib*128} WtT[m][k]*T16[ib*128+s][k]
//      WtT[m][ib*128+r] = sum_s Ut[m][s]*Dinv[ib][r][s]
// ---------------------------------------------------------------------------
__global__ __launch_bounds__(256, 1) void fused_solve(const half_t* __restrict__ T16,
                                                      const half_t* __restrict__ VhT,
                                                      const half_t* __restrict__ Dinv,
                                                      half_t* __restrict__ WtT) {
  __shared__ half_t bufA[2][64 * 64];    // 2 x 8KB  A dbuf (64 rows x 64 k)
  __shared__ half_t bufB[2][128 * 64];   // 2 x 16KB B dbuf (128 rows x 64 k)
  __shared__ half_t Us[64 * 128];        // 16KB (phase 2 -> 4)
  __shared__ half_t sD[128 * 128];       // 32KB (staged at panel top)  => 96KB
  int tid = threadIdx.x, lane = tid & 63, wave = tid >> 6;
  int ln15 = lane & 15, quad = lane >> 4;
  int m0 = blockIdx.x * 64;
  int wr = (wave & 1) * 32, wc = (wave >> 1) * 64;

  for (int ib = 0; ib < 14; ++ib) {
    // drain prev panel's WtT stores (vmcnt0+barrier): store->load visibility
    // for this panel's K-loop reads; frees Us/sD/bufs. Clean vmcnt slate.
    __syncthreads();
    // stage Dinv block ib -> sD (one-shot DMA; retired by first K-loop
    // vmcnt wait or, for ib=0, by the pre-phase-4 __syncthreads)
    for (int it = 0; it < 8; ++it) {
      int ch = it * 256 + tid;
      int row = ch >> 4, sc = ch & 15;
      const half_t* g = Dinv + (size_t)ib * 16384 + (size_t)row * 128 + ((sc ^ (row & 15)) << 3);
      half_t* l = sD + (size_t)(it * 256 + (tid & 192)) * 8;
      __builtin_amdgcn_global_load_lds(
          (const __attribute__((address_space(1))) uint32_t*)(const void*)g,
          (__attribute__((address_space(3))) uint32_t*)(void*)l, 16, 0, 0);
    }

    float4v acc[2][4] = {};
    int Ksteps = ib * 2;               // BK=64 steps
    if (Ksteps > 0) {
      // 4 statically-named register groups, 6 x half8 (16B) each.
      half8 g0[6], g1[6], g2[6], g3[6];
      auto LOADG = [&](half8 (&G)[6], int k) {
        if (k >= Ksteps) return;
        int k0 = k * 64;
#pragma unroll
        for (int i = 0; i < 2; ++i) {             // A: 64x64 tile, 512 chunks
          int ch = tid + 256 * i;
          int row = ch >> 3, kc = ch & 7, swz = kc ^ (row & 7);
          G[i] = *(const half8*)(WtT + (size_t)(m0 + row) * D_DIM + k0 + swz * 8);
        }
#pragma unroll
        for (int i = 0; i < 4; ++i) {             // B: 128x64 tile, 1024 chunks
          int ch = tid + 256 * i;
          int row = ch >> 3, kc = ch & 7, swz = kc ^ (row & 7);
          G[2 + i] = *(const half8*)(T16 + (size_t)(ib * 128 + row) * D_DIM + k0 + swz * 8);
        }
      };
      int kb = 0;
      auto STEP = [&](half8 (&G)[6]) {
        int rem = Ksteps - 1 - kb;     // groups that must stay in flight
        if (rem >= 3)      asm volatile("s_waitcnt vmcnt(18)" ::: "memory");
        else if (rem == 2) asm volatile("s_waitcnt vmcnt(12)" ::: "memory");
        else if (rem == 1) asm volatile("s_waitcnt vmcnt(6)"  ::: "memory");
        else               asm volatile("s_waitcnt vmcnt(0)"  ::: "memory");
        __builtin_amdgcn_sched_barrier(0);
        int p = kb & 1;
#pragma unroll
        for (int i = 0; i < 2; ++i)
          *(half8*)(&bufA[p][0] + (size_t)(tid + 256 * i) * 8) = G[i];
#pragma unroll
        for (int i = 0; i < 4; ++i)
          *(half8*)(&bufB[p][0] + (size_t)(tid + 256 * i) * 8) = G[2 + i];
        __builtin_amdgcn_sched_barrier(0);
        asm volatile("s_waitcnt lgkmcnt(0)" ::: "memory");   // writes landed
        __builtin_amdgcn_s_barrier();                        // visible to all
        __builtin_amdgcn_sched_barrier(0);
        half8 af[2], bf[4];
#pragma unroll
        for (int q = 0; q < 2; ++q) {
#pragma unroll
          for (int i = 0; i < 2; ++i) af[i] = frag64(&bufA[p][0], wr + i * 16 + ln15, q * 4 + quad);
#pragma unroll
          for (int j = 0; j < 4; ++j) bf[j] = frag64(&bufB[p][0], wc + j * 16 + ln15, q * 4 + quad);
#pragma unroll
          for (int i = 0; i < 2; ++i)
#pragma unroll
            for (int j = 0; j < 4; ++j)
              acc[i][j] = __builtin_amdgcn_mfma_f32_16x16x32_f16(af[i], bf[j], acc[i][j], 0, 0, 0);
        }
        __builtin_amdgcn_sched_barrier(0);
        __builtin_amdgcn_s_barrier();   // reads done before buf[p] reused (kb+2)
        if (kb + 4 < Ksteps) LOADG(G, kb + 4);
        ++kb;
      };
      LOADG(g0, 0); LOADG(g1, 1); LOADG(g2, 2); LOADG(g3, 3);
      while (true) {
        STEP(g0); if (kb == Ksteps) break;
        STEP(g1); if (kb == Ksteps) break;
        STEP(g2); if (kb == Ksteps) break;
        STEP(g3); if (kb == Ksteps) break;
      }
    }
    // phase 2: Ut = 2*VnT - acc  -> Us (A-operand layout, swizzled)
#pragma unroll
    for (int i = 0; i < 2; ++i)
#pragma unroll
      for (int j = 0; j < 4; ++j)
#pragma unroll
        for (int rg = 0; rg < 4; ++rg) {
          int rl = wr + i * 16 + quad * 4 + rg;     // local m
          int cl = wc + j * 16 + ln15;              // local s (panel row)
          float vn = (float)VhT[(size_t)(m0 + rl) * D_DIM + ib * 128 + cl];
          float u = 2.f * vn - acc[i][j][rg];
          int sc = cl >> 3, off = cl & 7;
          Us[rl * 128 + ((sc ^ (rl & 15)) << 3) + off] = (half_t)u;
        }
    __syncthreads();   // full drain: sD DMA (vmcnt) + Us ds_writes visible
    // phase 4: WtT-panel = Ut * Dinv^T  (K=128)
    float4v a2[2][4] = {};
#pragma unroll
    for (int kk = 0; kk < 4; ++kk) {
      half8 af[2], bf[4];
#pragma unroll
      for (int i = 0; i < 2; ++i) af[i] = frag128(Us, wr + i * 16 + ln15, kk * 4 + quad);
#pragma unroll
      for (int j = 0; j < 4; ++j) bf[j] = frag128(sD, wc + j * 16 + ln15, kk * 4 + quad);
#pragma unroll
      for (int i = 0; i < 2; ++i)
#pragma unroll
        for (int j = 0; j < 4; ++j)
          a2[i][j] = __builtin_amdgcn_mfma_f32_16x16x32_f16(af[i], bf[j], a2[i][j], 0, 0, 0);
    }
#pragma unroll
    for (int i = 0; i < 2; ++i)
#pragma unroll
      for (int j = 0; j < 4; ++j)
#pragma unroll
        for (int rg = 0; rg < 4; ++rg) {
          int rl = wr + i * 16 + quad * 4 + rg;
          int cl = wc + j * 16 + ln15;
          WtT[(size_t)(m0 + rl) * D_DIM + ib * 128 + cl] = (half_t)a2[i][j][rg];
        }
  }
}

// ---------------------------------------------------------------------------
extern "C" void kernel_launch(void* const* d_in, const int* in_sizes, int n_in,
                              void* d_out, int out_size, void* d_ws, size_t ws_size,
                              hipStream_t stream) {
  (void)in_sizes; (void)n_in; (void)out_size; (void)ws_size;
  const float* X = (const float*)d_in[0];   // (1792, 8192) fp32
  const float* U = (const float*)d_in[1];   // (1792, 1792) fp32
  float* out = (float*)d_out;               // (1792, 8192) fp32

  char* ws = (char*)d_ws;
  half_t* XT   = (half_t*)(ws);                    // 29,360,128 B
  half_t* Vh   = (half_t*)(ws + 29360128);         //  6,422,528 B
  half_t* VhT  = (half_t*)(ws + 35782656);         //  6,422,528 B
  half_t* T16  = (half_t*)(ws + 42205184);         //  6,422,528 B
  half_t* WtT  = (half_t*)(ws + 48627712);         //  6,422,528 B
  half_t* Dinv = (half_t*)(ws + 55050240);         //    458,752 B
  half_t* Pf   = (half_t*)(ws + 55508992);         //  6,422,528 B  (total ~62 MB)

  normalize_rows<<<dim3(D_DIM), dim3(256), 0, stream>>>(U, Vh);
  transpose_x<<<dim3(D_DIM / 64, B_DIM / 64), dim3(256), 0, stream>>>(X, XT);
  // T16 = 2*strict_tril(Vn Vn^T) directly (gram fused with build_T16; fp32 G gone)
  gemm_nt<0><<<dim3(14, 14), dim3(256), 0, stream>>>(Vh, Vh, nullptr, T16,
                                                     D_DIM, D_DIM, D_DIM, D_DIM);
  transpose_h<<<dim3(28, 28), dim3(256), 0, stream>>>(Vh, VhT);
  diag_inv<<<dim3(448), dim3(256), 0, stream>>>(T16, Dinv);
  // one-launch blocked forward substitution: WtT = (T^{-1} 2Vn)^T
  fused_solve<<<dim3(28), dim3(256), 0, stream>>>(T16, VhT, Dinv, WtT);
  // Pf = I - Wt^T Vn :  Pf[m][n] = delta(m,n) - sum_k WtT[m][k]*VhT[n][k]
  gemm_nt<1><<<dim3(14, 14), dim3(256), 0, stream>>>(WtT, VhT, nullptr, Pf,
                                                     D_DIM, D_DIM, D_DIM, D_DIM);
  // out = Pf X :  out[i][j] = sum_k Pf[i][k]*XT[j][k]
  gemm_nt<2><<<dim3(64, 14), dim3(256), 0, stream>>>(Pf, XT, out, nullptr,
                                                     D_DIM, D_DIM, D_DIM, B_DIM);
}

// Round 7
// 460.277 us; speedup vs baseline: 2.0734x; 1.2077x over previous
//
#include <hip/hip_runtime.h>
#include <stdint.h>
#include <stddef.h>

typedef _Float16 half_t;
typedef _Float16 half8 __attribute__((ext_vector_type(8)));
typedef float float4v __attribute__((ext_vector_type(4)));

#define D_DIM 1792
#define B_DIM 8192
#define LD D_DIM

// ---------------------------------------------------------------------------
// Async global->LDS staging of ROWS*32 fp16 tile (rows along K, NT layout).
// slot = chunk ^ ((row>>1)&3): every 8-lane b128 phase covers all 8 bank-quads
// (conflict-free — verified: SQ_LDS_BANK_CONFLICT 6.4e6 -> 0).
// ---------------------------------------------------------------------------
__device__ __forceinline__ void stage_rows(const half_t* __restrict__ src, int row0, int ld,
                                           int k0, half_t* dst, int nchunks, int tid) {
  for (int base = 0; base < nchunks; base += 256) {
    int ch  = base + tid;
    int row = ch >> 2, kc = ch & 3;
    int swz = kc ^ ((row >> 1) & 3);
    const half_t* g = src + (size_t)(row0 + row) * ld + k0 + swz * 8;
    half_t* l = dst + (size_t)(base + (tid & 192)) * 8;   // wave-uniform base; HW adds lane*16B
    __builtin_amdgcn_global_load_lds(
        (const __attribute__((address_space(1))) uint32_t*)(const void*)g,
        (__attribute__((address_space(3))) uint32_t*)(void*)l, 16, 0, 0);
  }
}

// ---------------------------------------------------------------------------
// FULL-LINE staging for fused_solve (R3-best). Tile rows are 64 halves (128B)
// wide: each global row = one aligned 128B L2 line. slot = kc ^ (row&7):
// conflict-free. LDS dest linear; pre-swizzled global source + same swizzle
// on read (both-sides-or-neither).
// ---------------------------------------------------------------------------
__device__ __forceinline__ void stage_rows64(const half_t* __restrict__ src, int row0, int ld,
                                             int k0, half_t* dst, int nchunks, int tid) {
  for (int base = 0; base < nchunks; base += 256) {
    int ch  = base + tid;
    int row = ch >> 3, kc = ch & 7;
    int swz = kc ^ (row & 7);
    const half_t* g = src + (size_t)(row0 + row) * ld + k0 + swz * 8;
    half_t* l = dst + (size_t)(base + (tid & 192)) * 8;
    __builtin_amdgcn_global_load_lds(
        (const __attribute__((address_space(1))) uint32_t*)(const void*)g,
        (__attribute__((address_space(3))) uint32_t*)(void*)l, 16, 0, 0);
  }
}

__device__ __forceinline__ half8 frag32(const half_t* lds, int row, int chunk) {
  int slot = chunk ^ ((row >> 1) & 3);
  return *(const half8*)(lds + row * 32 + slot * 8);
}
__device__ __forceinline__ half8 frag64(const half_t* lds, int row, int chunk) {
  int slot = chunk ^ (row & 7);
  return *(const half8*)(lds + row * 64 + slot * 8);
}
// 128-wide LDS rows (Us / Dinv in the solve): 2-way aliasing only (free).
__device__ __forceinline__ half8 frag128(const half_t* lds, int row, int chunk) {
  int slot = chunk ^ (row & 15);
  return *(const half8*)(lds + row * 128 + slot * 8);
}

// ---------------------------------------------------------------------------
// 1. Row-normalize U -> Vh (fp16). One block per row.
// ---------------------------------------------------------------------------
__global__ __launch_bounds__(256) void normalize_rows(const float* __restrict__ U,
                                                      half_t* __restrict__ Vh) {
  int r = blockIdx.x, t = threadIdx.x;
  float v[7];
  float s = 0.f;
#pragma unroll
  for (int i = 0; i < 7; ++i) {
    v[i] = U[(size_t)r * D_DIM + t + i * 256];
    s += v[i] * v[i];
  }
#pragma unroll
  for (int m = 32; m; m >>= 1) s += __shfl_xor(s, m);
  __shared__ float red[4];
  __shared__ float tot;
  if ((t & 63) == 0) red[t >> 6] = s;
  __syncthreads();
  if (t == 0) tot = 1.0f / sqrtf(red[0] + red[1] + red[2] + red[3]);
  __syncthreads();
  float rn = tot;
#pragma unroll
  for (int i = 0; i < 7; ++i)
    Vh[(size_t)r * D_DIM + t + i * 256] = (half_t)(v[i] * rn);
}

// ---------------------------------------------------------------------------
// 2. Transpose X (fp32, D x B) -> XT (fp16, B x D). 64x64 LDS tiles.
// ---------------------------------------------------------------------------
__global__ __launch_bounds__(256) void transpose_x(const float* __restrict__ X,
                                                   half_t* __restrict__ XT) {
  __shared__ half_t t[64][68];
  int r0 = blockIdx.x * 64, c0 = blockIdx.y * 64;
  int tid = threadIdx.x;
#pragma unroll
  for (int i = 0; i < 16; ++i) {
    int f = tid + i * 256;
    int rr = f >> 6, cc = f & 63;
    t[rr][cc] = (half_t)X[(size_t)(r0 + rr) * B_DIM + c0 + cc];
  }
  __syncthreads();
#pragma unroll
  for (int i = 0; i < 16; ++i) {
    int f = tid + i * 256;
    int cc = f >> 6, rr = f & 63;
    XT[(size_t)(c0 + cc) * D_DIM + r0 + rr] = t[rr][cc];
  }
}

// ---------------------------------------------------------------------------
// 2b. Transpose Vh (fp16, D x D) -> VhT.
// ---------------------------------------------------------------------------
__global__ __launch_bounds__(256) void transpose_h(const half_t* __restrict__ Vh,
                                                   half_t* __restrict__ VhT) {
  __shared__ half_t t[64][68];
  int r0 = blockIdx.x * 64, c0 = blockIdx.y * 64;
  int tid = threadIdx.x;
#pragma unroll
  for (int i = 0; i < 16; ++i) {
    int f = tid + i * 256;
    int rr = f >> 6, cc = f & 63;
    t[rr][cc] = Vh[(size_t)(r0 + rr) * D_DIM + c0 + cc];
  }
  __syncthreads();
#pragma unroll
  for (int i = 0; i < 16; ++i) {
    int f = tid + i * 256;
    int cc = f >> 6, rr = f & 63;
    VhT[(size_t)(c0 + cc) * D_DIM + r0 + rr] = t[rr][cc];
  }
}

// ---------------------------------------------------------------------------
// 3. Big NT MFMA GEMM: acc[m][n] = sum_k A[m][k]*B[n][k], 128x128 tile.
//    R7: 2-PHASE pipeline (guide T3-minimum): stage next tile into the
//    OTHER static buffer pair BEFORE computing current; counted vmcnt(4)
//    keeps next-tile loads in flight across the compute (the old
//    __syncthreads drained vmcnt(0) of same-iteration loads = full latency
//    exposed every tile). Static sA0/sA1 (not runtime-indexed) so the
//    compiler can disambiguate DMA-vs-ds_read aliasing.
//    MODE 0 (gram->T16): triangular block skip; Ch = (c<r) ? 2*acc : 0  (fp16)
//    MODE 1 (Pf build):  Ch = (r==c ? 1 : 0) - acc                      (fp16)
//    MODE 2 (final):     Cf = acc (fp32), XCD-swizzled blockIdx (896=8*112)
// ---------------------------------------------------------------------------
template <int MODE>
__global__ __launch_bounds__(256) void gemm_nt(const half_t* __restrict__ A,
                                               const half_t* __restrict__ B,
                                               float* __restrict__ Cf, half_t* __restrict__ Ch,
                                               int K, int lda, int ldb, int ldc) {
  int bx = blockIdx.x, by = blockIdx.y;
  if constexpr (MODE == 2) {
    // T1 XCD swizzle: 896 workgroups, 8 XCDs, 112/XCD (bijective).
    int id = bx + gridDim.x * by;
    int t = (id & 7) * 112 + (id >> 3);
    bx = t % gridDim.x;
    by = t / gridDim.x;
  }
  int m0 = by * 128, n0 = bx * 128;
  if constexpr (MODE == 0) { if (n0 > m0) return; }   // gram: lower+diag blocks only
  __shared__ half_t sA0[128 * 32], sB0[128 * 32];
  __shared__ half_t sA1[128 * 32], sB1[128 * 32];
  int tid = threadIdx.x, lane = tid & 63, wave = tid >> 6;
  int ln15 = lane & 15, quad = lane >> 4;
  int wr = (wave & 1) * 64, wc = (wave >> 1) * 64;
  float4v acc[4][4] = {};
  int KB = K / 32;                     // always even here (56 / 56 / 56)
  auto compute = [&](const half_t* cA, const half_t* cB) {
    half8 af[4], bf[4];
#pragma unroll
    for (int i = 0; i < 4; ++i) af[i] = frag32(cA, wr + i * 16 + ln15, quad);
#pragma unroll
    for (int j = 0; j < 4; ++j) bf[j] = frag32(cB, wc + j * 16 + ln15, quad);
#pragma unroll
    for (int i = 0; i < 4; ++i)
#pragma unroll
      for (int j = 0; j < 4; ++j)
        acc[i][j] = __builtin_amdgcn_mfma_f32_16x16x32_f16(af[i], bf[j], acc[i][j], 0, 0, 0);
  };
  // prologue: stage tile 0 into buffer pair 0 (4 loads/thread)
  stage_rows(A, m0, lda, 0, sA0, 512, tid);
  stage_rows(B, n0, ldb, 0, sB0, 512, tid);
  for (int kb = 0; kb < KB; kb += 2) {
    // stage tile kb+1 into pair 1, then wait only for pair-0's 4 loads
    stage_rows(A, m0, lda, (kb + 1) * 32, sA1, 512, tid);
    stage_rows(B, n0, ldb, (kb + 1) * 32, sB1, 512, tid);
    asm volatile("s_waitcnt vmcnt(4)" ::: "memory");
    __builtin_amdgcn_s_barrier();
    __builtin_amdgcn_sched_barrier(0);
    compute(sA0, sB0);
    __builtin_amdgcn_sched_barrier(0);
    __builtin_amdgcn_s_barrier();        // pair-0 reads done -> reusable
    if (kb + 2 < KB) {
      stage_rows(A, m0, lda, (kb + 2) * 32, sA0, 512, tid);
      stage_rows(B, n0, ldb, (kb + 2) * 32, sB0, 512, tid);
      asm volatile("s_waitcnt vmcnt(4)" ::: "memory");
    } else {
      asm volatile("s_waitcnt vmcnt(0)" ::: "memory");
    }
    __builtin_amdgcn_s_barrier();
    __builtin_amdgcn_sched_barrier(0);
    compute(sA1, sB1);
    __builtin_amdgcn_sched_barrier(0);
    __builtin_amdgcn_s_barrier();        // pair-1 reads done -> reusable
  }
#pragma unroll
  for (int i = 0; i < 4; ++i)
#pragma unroll
    for (int j = 0; j < 4; ++j)
#pragma unroll
      for (int rg = 0; rg < 4; ++rg) {
        int row = m0 + wr + i * 16 + quad * 4 + rg;
        int col = n0 + wc + j * 16 + ln15;
        size_t idx = (size_t)row * ldc + col;
        float v = acc[i][j][rg];
        if constexpr (MODE == 0) Ch[idx] = (col < row) ? (half_t)(2.0f * v) : (half_t)0.0f;
        else if constexpr (MODE == 1) Ch[idx] = (half_t)(((row == col) ? 1.0f : 0.0f) - v);
        else Cf[idx] = v;
      }
}

// ---------------------------------------------------------------------------
// 4. Invert 14 diagonal 128x128 unit-lower-triangular blocks of T (from T16).
//    One wave per column; forward substitution. -> Dinv (fp16, 14x128x128)
// ---------------------------------------------------------------------------
__global__ __launch_bounds__(256) void diag_inv(const half_t* __restrict__ T16,
                                                half_t* __restrict__ Dinv) {
  int b = blockIdx.x >> 5;        // block 0..13
  int cg = blockIdx.x & 31;       // column group
  int wave = threadIdx.x >> 6, ln = threadIdx.x & 63;
  int c = cg * 4 + wave;          // this wave's column (0..127)
  __shared__ float Ls[128][128];
  __shared__ float xw[4][128];
  for (int i = 0; i < 64; ++i) {
    int f = threadIdx.x + i * 256;
    int r = f >> 7, cc = f & 127;
    Ls[r][cc] = (cc < r) ? (float)T16[(size_t)(b * 128 + r) * D_DIM + b * 128 + cc] : 0.0f;
  }
  __syncthreads();
  float xlo = (ln == 0) ? 1.f : 0.f, xhi = 0.f;
  for (int r = c + 1; r < 128; ++r) {
    float ta = 0.f;
    int j0 = c + ln, j1 = c + 64 + ln;
    if (j0 < r) ta += Ls[r][j0] * xlo;
    if (j1 < r) ta += Ls[r][j1] * xhi;
#pragma unroll
    for (int m = 32; m; m >>= 1) ta += __shfl_xor(ta, m);
    float xr = -ta;
    if (j0 == r) xlo = xr;
    if (j1 == r) xhi = xr;
    if (ln == 0) xw[wave][r] = xr;
  }
  __syncthreads();
  for (int rr = ln; rr < 128; rr += 64) {
    float val = (rr < c) ? 0.f : ((rr == c) ? 1.f : xw[wave][rr]);
    Dinv[(size_t)b * 16384 + (size_t)rr * 128 + c] = (half_t)val;
  }
}

// ---------------------------------------------------------------------------
// 5. FUSED blocked forward substitution — ONE launch. R3-BEST (155us),
//    restored verbatim: all-static 144KB LDS, depth-4 coop-DMA staging ring
//    (PDIST=3, counted vmcnt 18/12/6/0), full-line stage_rows64, hoisted
//    per-panel Dinv DMA + VhT fragment loads. Six structural variants
//    (R1/R3/R4/R5/R6) bracket this as the empirical best; cost scales with
//    staged bytes (per-CU load-path floor), so further in-loop pipelining
//    is not the lever here.
//    Per panel ib:
//      Ut[m][s] = 2*Vn[ib*128+s][m] - sum_{k<ib*128} WtT[m][k]*T16[ib*128+s][k]
//      WtT[m][ib*128+r] = sum_s Ut[m][s]*Dinv[ib][r][s]
// ---------------------------------------------------------------------------
#define NBUF 4
#define PDIST 3
// per-buffer (halves): sA 64x64 = 4096, sB 128x64 = 8192 -> 12288 (24KB)
#define BUF_HALVES 12288

__global__ __launch_bounds__(256) void fused_solve(const half_t* __restrict__ T16,
                                                   const half_t* __restrict__ VhT,
                                                   const half_t* __restrict__ Dinv,
                                                   half_t* __restrict__ WtT) {
  __shared__ half_t ring[NBUF * BUF_HALVES];   // 96KB staging ring
  __shared__ half_t Us[64 * 128];              // 16KB (phase 2 -> 4)
  __shared__ half_t sD[128 * 128];             // 32KB (staged at panel top)
  int tid = threadIdx.x, lane = tid & 63, wave = tid >> 6;
  int ln15 = lane & 15, quad = lane >> 4;
  int m0 = blockIdx.x * 64;
  int wr = (wave & 1) * 32, wc = (wave >> 1) * 64;
  for (int ib = 0; ib < 14; ++ib) {
    // drain prev panel's WtT stores (vmcnt0) + phase-4 LDS reads; frees sD/ring
    __syncthreads();
    // --- hoisted per-panel loads (K-loop-independent; latency hides under it)
    float vnf[2][4][4];
#pragma unroll
    for (int i = 0; i < 2; ++i)
#pragma unroll
      for (int j = 0; j < 4; ++j)
#pragma unroll
        for (int rg = 0; rg < 4; ++rg)
          vnf[i][j][rg] = (float)VhT[(size_t)(m0 + wr + i * 16 + quad * 4 + rg) * D_DIM
                                     + ib * 128 + wc + j * 16 + ln15];
    // stage Dinv block ib -> sD (global-side swizzle for 128-wide rows)
    for (int it = 0; it < 8; ++it) {
      int ch = it * 256 + tid;
      int row = ch >> 4, sc = ch & 15;
      const half_t* g = Dinv + (size_t)ib * 16384 + (size_t)row * 128 + ((sc ^ (row & 15)) << 3);
      half_t* l = sD + (size_t)(it * 256 + (tid & 192)) * 8;
      __builtin_amdgcn_global_load_lds(
          (const __attribute__((address_space(1))) uint32_t*)(const void*)g,
          (__attribute__((address_space(3))) uint32_t*)(void*)l, 16, 0, 0);
    }
    __builtin_amdgcn_sched_barrier(0);   // keep hoisted loads above the K-loop
    float4v acc[2][4] = {};
    int Ksteps = ib * 2;               // BK=64 steps
    if (Ksteps > 0) {
      // prologue: fill up to PDIST buffers ahead (6 loads/thread each)
      int npre = Ksteps < PDIST ? Ksteps : PDIST;
      for (int p = 0; p < npre; ++p) {
        half_t* bA = ring + p * BUF_HALVES;
        half_t* bB = bA + 4096;
        int k0 = p * 64;
        stage_rows64(WtT, m0, D_DIM, k0, bA, 512, tid);
        stage_rows64(T16, ib * 128, D_DIM, k0, bB, 1024, tid);
      }
      for (int kb = 0; kb < Ksteps; ++kb) {
        if (kb + PDIST < Ksteps) {
          int slot = (kb + PDIST) % NBUF, k0 = (kb + PDIST) * 64;
          half_t* bA = ring + slot * BUF_HALVES;
          half_t* bB = bA + 4096;
          stage_rows64(WtT, m0, D_DIM, k0, bA, 512, tid);
          stage_rows64(T16, ib * 128, D_DIM, k0, bB, 1024, tid);
        }
        // buffers in flight ahead of kb = min(Ksteps-1-kb, PDIST); 6 loads each.
        int R = Ksteps - 1 - kb;
        if (R >= 3)      asm volatile("s_waitcnt vmcnt(18)" ::: "memory");
        else if (R == 2) asm volatile("s_waitcnt vmcnt(12)" ::: "memory");
        else if (R == 1) asm volatile("s_waitcnt vmcnt(6)"  ::: "memory");
        else             asm volatile("s_waitcnt vmcnt(0)"  ::: "memory");
        __builtin_amdgcn_s_barrier();        // all waves' buf[kb] loads landed
        __builtin_amdgcn_sched_barrier(0);   // pin ds_reads below the barrier
        half_t* cA = ring + (kb % NBUF) * BUF_HALVES;
        half_t* cB = cA + 4096;
        half8 af[2], bf[4];
#pragma unroll
        for (int q = 0; q < 2; ++q) {
#pragma unroll
          for (int i = 0; i < 2; ++i) af[i] = frag64(cA, wr + i * 16 + ln15, q * 4 + quad);
#pragma unroll
          for (int j = 0; j < 4; ++j) bf[j] = frag64(cB, wc + j * 16 + ln15, q * 4 + quad);
#pragma unroll
          for (int i = 0; i < 2; ++i)
#pragma unroll
            for (int j = 0; j < 4; ++j)
              acc[i][j] = __builtin_amdgcn_mfma_f32_16x16x32_f16(af[i], bf[j], acc[i][j], 0, 0, 0);
        }
        __builtin_amdgcn_sched_barrier(0);   // pin ds_reads above the barrier
        __builtin_amdgcn_s_barrier();        // buf[kb] now safe to overwrite
      }
    }
    // phase 2: Ut = 2*VnT - acc  -> Us (A-operand layout, swizzled)
#pragma unroll
    for (int i = 0; i < 2; ++i)
#pragma unroll
      for (int j = 0; j < 4; ++j)
#pragma unroll
        for (int rg = 0; rg < 4; ++rg) {
          int rl = wr + i * 16 + quad * 4 + rg;     // local m
          int cl = wc + j * 16 + ln15;              // local s (panel row)
          float u = 2.f * vnf[i][j][rg] - acc[i][j][rg];
          int sc = cl >> 3, off = cl & 7;
          Us[rl * 128 + ((sc ^ (rl & 15)) << 3) + off] = (half_t)u;
        }
    __syncthreads();   // full drain: sD loads (vmcnt) + Us ds_writes visible
    // phase 4: WtT-panel = Ut * Dinv^T  (K=128)
    float4v a2[2][4] = {};
#pragma unroll
    for (int kk = 0; kk < 4; ++kk) {
      half8 af[2], bf[4];
#pragma unroll
      for (int i = 0; i < 2; ++i) af[i] = frag128(Us, wr + i * 16 + ln15, kk * 4 + quad);
#pragma unroll
      for (int j = 0; j < 4; ++j) bf[j] = frag128(sD, wc + j * 16 + ln15, kk * 4 + quad);
#pragma unroll
      for (int i = 0; i < 2; ++i)
#pragma unroll
        for (int j = 0; j < 4; ++j)
          a2[i][j] = __builtin_amdgcn_mfma_f32_16x16x32_f16(af[i], bf[j], a2[i][j], 0, 0, 0);
    }
#pragma unroll
    for (int i = 0; i < 2; ++i)
#pragma unroll
      for (int j = 0; j < 4; ++j)
#pragma unroll
        for (int rg = 0; rg < 4; ++rg) {
          int rl = wr + i * 16 + quad * 4 + rg;
          int cl = wc + j * 16 + ln15;
          WtT[(size_t)(m0 + rl) * D_DIM + ib * 128 + cl] = (half_t)a2[i][j][rg];
        }
  }
}

// ---------------------------------------------------------------------------
extern "C" void kernel_launch(void* const* d_in, const int* in_sizes, int n_in,
                              void* d_out, int out_size, void* d_ws, size_t ws_size,
                              hipStream_t stream) {
  (void)in_sizes; (void)n_in; (void)out_size; (void)ws_size;
  const float* X = (const float*)d_in[0];   // (1792, 8192) fp32
  const float* U = (const float*)d_in[1];   // (1792, 1792) fp32
  float* out = (float*)d_out;               // (1792, 8192) fp32

  char* ws = (char*)d_ws;
  half_t* XT   = (half_t*)(ws);                    // 29,360,128 B
  half_t* Vh   = (half_t*)(ws + 29360128);         //  6,422,528 B
  half_t* VhT  = (half_t*)(ws + 35782656);         //  6,422,528 B
  half_t* T16  = (half_t*)(ws + 42205184);         //  6,422,528 B
  half_t* WtT  = (half_t*)(ws + 48627712);         //  6,422,528 B
  half_t* Dinv = (half_t*)(ws + 55050240);         //    458,752 B
  half_t* Pf   = (half_t*)(ws + 55508992);         //  6,422,528 B  (total ~62 MB)

  normalize_rows<<<dim3(D_DIM), dim3(256), 0, stream>>>(U, Vh);
  transpose_x<<<dim3(D_DIM / 64, B_DIM / 64), dim3(256), 0, stream>>>(X, XT);
  // T16 = 2*strict_tril(Vn Vn^T) directly (gram fused with build_T16; fp32 G gone)
  gemm_nt<0><<<dim3(14, 14), dim3(256), 0, stream>>>(Vh, Vh, nullptr, T16,
                                                     D_DIM, D_DIM, D_DIM, D_DIM);
  transpose_h<<<dim3(28, 28), dim3(256), 0, stream>>>(Vh, VhT);
  diag_inv<<<dim3(448), dim3(256), 0, stream>>>(T16, Dinv);
  // one-launch blocked forward substitution: WtT = (T^{-1} 2Vn)^T
  fused_solve<<<dim3(28), dim3(256), 0, stream>>>(T16, VhT, Dinv, WtT);
  // Pf = I - Wt^T Vn :  Pf[m][n] = delta(m,n) - sum_k WtT[m][k]*VhT[n][k]
  gemm_nt<1><<<dim3(14, 14), dim3(256), 0, stream>>>(WtT, VhT, nullptr, Pf,
                                                     D_DIM, D_DIM, D_DIM, D_DIM);
  // out = Pf X :  out[i][j] = sum_k Pf[i][k]*XT[j][k]
  gemm_nt<2><<<dim3(64, 14), dim3(256), 0, stream>>>(Pf, XT, out, nullptr,
                                                     D_DIM, D_DIM, D_DIM, B_DIM);
}